// Round 1
// baseline (217.853 us; speedup 1.0000x reference)
//
#include <hip/hip_runtime.h>

#define BS 2
#define NM 10
#define NA 8400
#define NC 80
#define NBIN 36
#define KTOP 13
#define NRECT (BS*NM*3)   // 60 rects: (bm, level)

// ---------------------------------------------------------------
// Closed-form in-box anchor rectangle for (bm, lv), endpoint-corrected
// with the exact float test the reference uses; membership is exact.
// ---------------------------------------------------------------
__device__ __forceinline__ void rect_one(int bm, int lv,
    const float* __restrict__ gtb, const float* __restrict__ mgt,
    int& x0, int& y0, int& cx, int& cnt, int& n, int& base){
  cnt = 0; x0 = 0; y0 = 0; cx = 0; n = 0; base = 0;
  if (mgt[bm] > 0.f){
    float s = (float)(8 << lv);
    n = 640 >> (3 + lv);                     // 80, 40, 20
    base = (lv == 0) ? 0 : ((lv == 1) ? 6400 : 8000);
    float lx = gtb[bm*4+0], ly = gtb[bm*4+1];
    float rx = gtb[bm*4+2], ry = gtb[bm*4+3];
    int a0 = (int)ceilf(lx/s - 0.5f); a0 = min(max(a0, 0), n);
    while (a0 > 0   &&  (((a0-1)+0.5f)*s - lx > 1e-9f)) a0--;
    while (a0 < n   && !(((a0  )+0.5f)*s - lx > 1e-9f)) a0++;
    int a1 = (int)floorf(rx/s - 0.5f); a1 = min(max(a1, -1), n-1);
    while (a1 < n-1 &&  (rx - ((a1+1)+0.5f)*s > 1e-9f)) a1++;
    while (a1 >= 0  && !(rx - ((a1  )+0.5f)*s > 1e-9f)) a1--;
    int b0 = (int)ceilf(ly/s - 0.5f); b0 = min(max(b0, 0), n);
    while (b0 > 0   &&  (((b0-1)+0.5f)*s - ly > 1e-9f)) b0--;
    while (b0 < n   && !(((b0  )+0.5f)*s - ly > 1e-9f)) b0++;
    int b1 = (int)floorf(ry/s - 0.5f); b1 = min(max(b1, -1), n-1);
    while (b1 < n-1 &&  (ry - ((b1+1)+0.5f)*s > 1e-9f)) b1++;
    while (b1 >= 0  && !(ry - ((b1  )+0.5f)*s > 1e-9f)) b1--;
    cx = max(0, a1 - a0 + 1);
    int cy = max(0, b1 - b0 + 1);
    cnt = cx * cy;
    x0 = a0; y0 = b0;
  }
}

__device__ __forceinline__ void rect_setup(int tid,
    const float* __restrict__ gtb, const float* __restrict__ mgt,
    int* sx0, int* sy0, int* scx, int* scum, int* sn, int* sbase){
  if (tid < NRECT){
    int bm = tid/3, lv = tid - bm*3;
    int x0, y0, cx, cnt, n, base;
    rect_one(bm, lv, gtb, mgt, x0, y0, cx, cnt, n, base);
    sx0[tid] = x0; sy0[tid] = y0; scx[tid] = cx;
    scum[tid] = cnt; sn[tid] = n; sbase[tid] = base;
  }
  __syncthreads();
  if (tid == 0){
    int acc = 0;
    for (int r = 0; r < NRECT; r++){ int c = scum[r]; scum[r] = acc; acc += c; }
    scum[NRECT] = acc;
  }
  __syncthreads();
}

__device__ __forceinline__ int pair_from_p(int p,
    const int* sx0, const int* sy0, const int* scx,
    const int* scum, const int* sn, const int* sbase){
  int r = 0;
  while (r < NRECT-1 && scum[r+1] <= p) r++;
  int idx = p - scum[r];
  int cx = scx[r];
  int yi = idx / cx;
  int xi = idx - yi*cx;
  int a = sbase[r] + (sy0[r] + yi)*sn[r] + (sx0[r] + xi);
  int bm = r/3;
  return bm*NA + a;
}

// ---------------- k_zero: coalesced zero of out regions + ws -----------------
__global__ void k_zero(float* __restrict__ out, float* __restrict__ wf){
  float4 z = make_float4(0.f,0.f,0.f,0.f);
  int gsz = gridDim.x*256, gtid = blockIdx.x*256 + threadIdx.x;
  // o_scores
  float4* a = (float4*)(out + 84000);
  for (int i = gtid; i < 1344000/4; i += gsz) a[i] = z;
  // o_gtdist + o_cent (contiguous)
  float4* b = (float4*)(out + 1612800);
  for (int i = gtid; i < (6048000+168000)/4; i += gsz) b[i] = z;
  // ws: w_align, w_ovl, w_mask, w_pa, w_po
  float4* c = (float4*)(wf + 16);
  for (int i = gtid; i < (3*BS*NM*NA + 40)/4; i += gsz) c[i] = z;
}

// ---------------------------------------------------------------
// k_dist v2: one WAVE per pair (4 pairs per block, no intra-pair barriers).
// Per pair: stage 360 (ang,dist) with a 36-bucket counting sort in LDS
// (LDS atomics + wave prefix scan; scatter order is arbitrary — selection
// is keyed lexicographically by (diff_bits, point_idx) so the result is
// order-independent and reproduces lax.top_k stable-tie semantics exactly).
// Per bin b (= lane): scan only buckets {b-1,b,b+1} (all points with
// circular diff <= ~10 deg provably live there). If window min-diff > 3
// -> masked (1e-6), no top-4 needed. Accept window top-4 iff 4th-best
// diff <= 9.99 (coverage guarantee with float-boundary margin), else
// rare exact fallback: full 360-point rescan for that lane.
// ---------------------------------------------------------------
__global__ __launch_bounds__(256)
void k_dist(const float* __restrict__ pds, const float* __restrict__ pdb,
            const float* __restrict__ anc, const int* __restrict__ gl,
            const float* __restrict__ gtb, const float* __restrict__ mgt,
            const float* __restrict__ coor,
            float* __restrict__ out, float* __restrict__ wf){
  float* o_gtdist  = out + 1612800;
  float* w_align = wf + 16;
  float* w_ovl   = w_align + BS*NM*NA;

  __shared__ int sx0[NRECT], sy0[NRECT], scx[NRECT], scum[NRECT+1], sn[NRECT], sbase[NRECT];
  __shared__ float2 s_ad[4][360];           // (ang, dist) in bucket-sorted order
  __shared__ unsigned short s_ix[4][360];   // original point index
  __shared__ int s_cnt[4][NBIN];
  __shared__ int s_off[4][NBIN+1];
  __shared__ int s_cur[4][NBIN];

  int tid = threadIdx.x;
  int lane = tid & 63, wv = tid >> 6;

  rect_setup(tid, gtb, mgt, sx0, sy0, scx, scum, sn, sbase);
  int total = scum[NRECT];

  for (int p = blockIdx.x*4 + wv; p < total; p += gridDim.x*4){
    int t = pair_from_p(p, sx0, sy0, scx, scum, sn, sbase);
    int a = t % NA; int bm = t / NA; int bb = bm / NM;
    float ax = anc[2*a], ay = anc[2*a+1];
    const float2* cc = (const float2*)(coor + bm*720);

    if (lane < NBIN) s_cnt[wv][lane] = 0;

    float angR[6], dstR[6]; int buR[6];
#pragma unroll
    for (int r = 0; r < 6; r++){
      int i = r*64 + lane;
      angR[r] = 0.f; dstR[r] = 0.f; buR[r] = -1;
      if (i < 360){
        float2 cxy = cc[i];
        float dx = cxy.x - ax;
        float dy = cxy.y - ay;
        float dist = sqrtf(dx*dx + dy*dy);
        float an = atan2f(dy, dx) * 57.29577951308232f;
        if (an < 0.f) an += 360.f;
        int bu = (int)(an * 0.1f); bu = min(bu, NBIN-1);
        angR[r] = an; dstR[r] = dist; buR[r] = bu;
        atomicAdd(&s_cnt[wv][bu], 1);
      }
    }
    // exclusive prefix over 36 bucket counts (wave-wide shfl scan)
    int c = (lane < NBIN) ? s_cnt[wv][lane] : 0;
    int incl = c;
#pragma unroll
    for (int st = 1; st < 64; st <<= 1){
      int o = __shfl_up(incl, st);
      if (lane >= st) incl += o;
    }
    if (lane < NBIN){ s_off[wv][lane+1] = incl; s_cur[wv][lane] = incl - c; }
    if (lane == 0) s_off[wv][0] = 0;
    // scatter into bucket-sorted order (order within bucket arbitrary)
#pragma unroll
    for (int r = 0; r < 6; r++){
      if (buR[r] >= 0){
        int pos = atomicAdd(&s_cur[wv][buR[r]], 1);
        s_ad[wv][pos] = make_float2(angR[r], dstR[r]);
        s_ix[wv][pos] = (unsigned short)(r*64 + lane);
      }
    }

    float sum_min = 0.f, sum_max = 0.f;
    if (lane < NBIN){
      float th = (float)(lane*10);
      int r0s, r0e, r1s, r1e;
      if (lane == 0)      { r0s = s_off[wv][35]; r0e = s_off[wv][36]; r1s = 0; r1e = s_off[wv][2]; }
      else if (lane == 35){ r0s = s_off[wv][34]; r0e = s_off[wv][36]; r1s = 0; r1e = s_off[wv][1]; }
      else                { r0s = s_off[wv][lane-1]; r0e = s_off[wv][lane+2]; r1s = 0; r1e = 0; }

      unsigned long long k0,k1,k2,k3;
      float p0,p1,p2,p3;
      k0=k1=k2=k3=0xFFFFFFFFFFFFFFFFull;
      p0=p1=p2=p3=0.f;
#define EVAL(J) { \
        float2 ad = s_ad[wv][J]; \
        unsigned int ixv = s_ix[wv][J]; \
        float df = fabsf(ad.x - th); \
        df = fminf(df, 360.f - df); \
        unsigned long long key = ((unsigned long long)__float_as_uint(df) << 32) | ixv; \
        if (key < k3){ \
          k3 = key; p3 = ad.y; \
          if (k3 < k2){ unsigned long long tk=k2; k2=k3; k3=tk; float tp=p2; p2=p3; p3=tp; } \
          if (k2 < k1){ unsigned long long tk=k1; k1=k2; k2=tk; float tp=p1; p1=p2; p2=tp; } \
          if (k1 < k0){ unsigned long long tk=k0; k0=k1; k1=tk; float tp=p0; p0=p1; p1=tp; } \
        } }
      for (int j = r0s; j < r0e; j++) EVAL(j)
      for (int j = r1s; j < r1e; j++) EVAL(j)

      float m  = __uint_as_float((unsigned int)(k0 >> 32));
      float d4 = __uint_as_float((unsigned int)(k3 >> 32));
      float res;
      if (!(m <= 3.0f)){          // window-min > 3 (or empty window) => masked
        res = 1e-6f;
      } else {
        if (!(d4 <= 9.99f)){      // coverage not guaranteed -> exact fallback
          k0=k1=k2=k3=0xFFFFFFFFFFFFFFFFull;
          p0=p1=p2=p3=0.f;
          for (int j = 0; j < 360; j++) EVAL(j)
        }
        res = fmaxf(fmaxf(fmaxf(p0,p1),fmaxf(p2,p3)), 1e-6f);
      }
      o_gtdist[(size_t)t*NBIN + lane] = res;
      float pr = pdb[((size_t)bb*NA + a)*NBIN + lane];
      sum_max = fmaxf(res, pr);
      sum_min = fmaxf(fminf(res, pr), 1e-6f);
    }
#undef EVAL
    for (int off = 32; off > 0; off >>= 1){
      sum_min += __shfl_down(sum_min, off);
      sum_max += __shfl_down(sum_max, off);
    }
    if (lane == 0){
      float ov = sum_min / sum_max;
      int cls = gl[bm];
      float sc = pds[((size_t)bb*NA + a)*NC + cls];
      w_align[t] = sc * ov * ov * ov;
      w_ovl[t]   = ov;
    }
  }
}

// ---------------- top-13 per (b,m): rect-local candidates only --------------
__global__ __launch_bounds__(256)
void k_topk(const float* __restrict__ gtb, const float* __restrict__ mgt,
            const float* __restrict__ w_align, float* __restrict__ w_mask){
  int bm = blockIdx.x;
  const float* al = w_align + (size_t)bm*NA;
  int tid = threadIdx.x;
  __shared__ int rx0[3], ry0[3], rcx[3], rcum[4], rn[3], rbase[3];
  __shared__ float sv[256*KTOP];
  __shared__ int   si[256*KTOP];
  __shared__ float wv4[4];
  __shared__ int   wi4[4];

  if (tid < 3){
    int x0, y0, cx, cnt, n, base;
    rect_one(bm, tid, gtb, mgt, x0, y0, cx, cnt, n, base);
    rx0[tid]=x0; ry0[tid]=y0; rcx[tid]=cx; rcum[tid]=cnt; rn[tid]=n; rbase[tid]=base;
  }
  __syncthreads();
  if (tid == 0){
    int acc = 0;
#pragma unroll
    for (int r = 0; r < 3; r++){ int c = rcum[r]; rcum[r] = acc; acc += c; }
    rcum[3] = acc;
  }
  __syncthreads();
  int total = rcum[3];

  float v[KTOP]; int ix[KTOP];
#pragma unroll
  for (int j = 0; j < KTOP; j++){ v[j] = -1.f; ix[j] = 0x7fffffff; }
  for (int p = tid; p < total; p += 256){
    int r = (p >= rcum[1]) + (p >= rcum[2]);
    int idx = p - rcum[r];
    int cx = rcx[r];
    int yi = idx / cx;
    int xi = idx - yi*cx;
    int a = rbase[r] + (ry0[r] + yi)*rn[r] + (rx0[r] + xi);
    float x = al[a];
    if (x > v[KTOP-1]){
      v[KTOP-1] = x; ix[KTOP-1] = a;
#pragma unroll
      for (int j = KTOP-1; j > 0; j--){
        if (v[j] > v[j-1]){
          float tv = v[j-1]; v[j-1] = v[j]; v[j] = tv;
          int   ti = ix[j-1]; ix[j-1] = ix[j]; ix[j] = ti;
        }
      }
    }
  }
#pragma unroll
  for (int j = 0; j < KTOP; j++){ sv[tid*KTOP+j] = v[j]; si[tid*KTOP+j] = ix[j]; }

  int head = 0;
  int lane = tid & 63, wave = tid >> 6;
  for (int r = 0; r < KTOP; r++){
    float cv = sv[tid*KTOP + head];
    int   ci = si[tid*KTOP + head];
    float rv = cv; int ri = ci;
    for (int off = 32; off > 0; off >>= 1){
      float ov = __shfl_down(rv, off);
      int   oi = __shfl_down(ri, off);
      if (ov > rv || (ov == rv && oi < ri)){ rv = ov; ri = oi; }
    }
    if (lane == 0){ wv4[wave] = rv; wi4[wave] = ri; }
    __syncthreads();
    float Wv = wv4[0]; int Wi = wi4[0];
#pragma unroll
    for (int w = 1; w < 4; w++){
      float ov = wv4[w]; int oi = wi4[w];
      if (ov > Wv || (ov == Wv && oi < Wi)){ Wv = ov; Wi = oi; }
    }
    if (ci == Wi && head < KTOP-1) head++;
    if (tid == 0 && Wv > 0.f) w_mask[(size_t)bm*NA + Wi] = 1.f;
    __syncthreads();
  }
}

// ---------------- per-anchor finalize (+ fused pos_align/pos_ov atomics) ------
__global__ void k_final(const float* __restrict__ w_align, const float* __restrict__ w_ovl,
                        float* __restrict__ w_mask,
                        const int* __restrict__ gl, const float* __restrict__ gtb,
                        float* __restrict__ o_labels, float* __restrict__ o_bboxes,
                        float* __restrict__ o_maskpos, float* __restrict__ o_gtidx,
                        float* __restrict__ o_fg,
                        float* __restrict__ w_pa, float* __restrict__ w_po){
  int t = blockIdx.x*256 + threadIdx.x;
  if (t >= BS*NA) return;
  int a = t % NA, b = t / NA;
  float mp[NM];
  int fg = 0;
#pragma unroll
  for (int m = 0; m < NM; m++){
    mp[m] = w_mask[((size_t)(b*NM+m))*NA + a];
    fg += (mp[m] > 0.f) ? 1 : 0;
  }
  if (fg > 1){
    float bv = -1.f; int bi = 0;
#pragma unroll
    for (int m = 0; m < NM; m++){
      float v = w_ovl[((size_t)(b*NM+m))*NA + a];
      if (v > bv){ bv = v; bi = m; }
    }
#pragma unroll
    for (int m = 0; m < NM; m++){
      mp[m] = (m == bi) ? 1.f : 0.f;
      w_mask[((size_t)(b*NM+m))*NA + a] = mp[m];
    }
    fg = 1;
  }
  int tgt = 0;
#pragma unroll
  for (int m = NM-1; m >= 0; m--) if (mp[m] > 0.f) tgt = m;
#pragma unroll
  for (int m = 0; m < NM; m++) o_maskpos[((size_t)(b*NM+m))*NA + a] = mp[m];
  o_gtidx[t] = (float)tgt;
  o_fg[t] = (fg > 0) ? 1.f : 0.f;
  int lbl = gl[b*NM + tgt]; if (lbl < 0) lbl = 0;
  o_labels[t] = (float)lbl;
  const float* bx = gtb + (b*NM + tgt)*4;
  ((float4*)o_bboxes)[t] = make_float4(bx[0], bx[1], bx[2], bx[3]);
  if (fg > 0){
    int bmx = b*NM + tgt;
    float av  = w_align[(size_t)bmx*NA + a];
    float ovv = w_ovl[(size_t)bmx*NA + a];
    atomicMax((unsigned int*)&w_pa[bmx], __float_as_uint(av));
    atomicMax((unsigned int*)&w_po[bmx], __float_as_uint(ovv));
  }
}

// ---------------- fused tail: (A) gt_dist mask + centerness, (B) scores ------
#define NB_FIX 512
__global__ void k_fuse(const float* __restrict__ gtb, const float* __restrict__ mgt,
                       const float* __restrict__ w_mask, float* __restrict__ o_gtdist,
                       float* __restrict__ o_cent,
                       const float* __restrict__ w_align,
                       const float* __restrict__ w_pa, const float* __restrict__ w_po,
                       const float* __restrict__ o_labels, const float* __restrict__ o_fg,
                       const float* __restrict__ o_gtidx, float* __restrict__ o_scores){
  if (blockIdx.x < NB_FIX){
    __shared__ int sx0[NRECT], sy0[NRECT], scx[NRECT], scum[NRECT+1], sn[NRECT], sbase[NRECT];
    int tid = threadIdx.x;
    rect_setup(tid, gtb, mgt, sx0, sy0, scx, scum, sn, sbase);
    int total = scum[NRECT];
    int lane = tid & 63, wave = tid >> 6;
    for (int p = blockIdx.x*4 + wave; p < total; p += NB_FIX*4){
      int t = pair_from_p(p, sx0, sy0, scx, scum, sn, sbase);
      float m = w_mask[t];
      float* row = o_gtdist + (size_t)t*NBIN;
      if (m > 0.f){
        float vmin = 1e30f, vmax = 0.f;
        if (lane < NBIN){
          float v = row[lane];
          vmin = v; vmax = v;
        }
        for (int off = 32; off > 0; off >>= 1){
          vmin = fminf(vmin, __shfl_down(vmin, off));
          vmax = fmaxf(vmax, __shfl_down(vmax, off));
        }
        if (lane == 0) o_cent[t] = sqrtf(vmin / vmax);
      } else {
        if (lane < NBIN) row[lane] = 0.f;
      }
    }
  } else {
    int t = (blockIdx.x - NB_FIX)*256 + threadIdx.x;
    if (t < BS*NA && o_fg[t] > 0.f){
      int a = t % NA, b = t / NA;
      int m = (int)o_gtidx[t];
      int bm = b*NM + m;
      float av = w_align[(size_t)bm*NA + a];
      float norm = av * w_po[bm] / (w_pa[bm] + 1e-9f);
      int lbl = (int)o_labels[t];
      o_scores[(size_t)t*NC + lbl] = norm;
    }
  }
}

extern "C" void kernel_launch(void* const* d_in, const int* in_sizes, int n_in,
                              void* d_out, int out_size, void* d_ws, size_t ws_size,
                              hipStream_t stream){
  const float* pds  = (const float*)d_in[0]; // (2,8400,80)
  const float* pdb  = (const float*)d_in[1]; // (2,8400,36)
  const float* anc  = (const float*)d_in[2]; // (8400,2)
  const int*   gl   = (const int*)  d_in[3]; // (2,10,1)
  const float* gtb  = (const float*)d_in[4]; // (2,10,4)
  const float* mgt  = (const float*)d_in[5]; // (2,10,1)
  const float* coor = (const float*)d_in[6]; // (2,10,720)

  float* out = (float*)d_out;
  float* o_labels  = out;                                 // 16800
  float* o_bboxes  = o_labels + BS*NA;                    // 67200
  float* o_scores  = o_bboxes + BS*NA*4;                  // 1344000
  float* o_maskpos = o_scores + (size_t)BS*NA*NC;         // 168000
  float* o_gtidx   = o_maskpos + BS*NM*NA;                // 16800
  float* o_gtdist  = o_gtidx + BS*NA;                     // 6048000
  float* o_cent    = o_gtdist + (size_t)BS*NM*NA*NBIN;    // 168000
  float* o_fg      = o_cent + BS*NM*NA;                   // 16800

  float* wf      = (float*)d_ws;
  float* w_align = wf + 16;
  float* w_ovl   = w_align + BS*NM*NA;
  float* w_mask  = w_ovl + BS*NM*NA;
  float* w_pa    = w_mask + BS*NM*NA;
  float* w_po    = w_pa + BS*NM;

  k_zero<<<2048, 256, 0, stream>>>(out, wf);
  k_dist<<<1536, 256, 0, stream>>>(pds, pdb, anc, gl, gtb, mgt, coor, out, wf);
  k_topk<<<BS*NM, 256, 0, stream>>>(gtb, mgt, w_align, w_mask);
  k_final<<<(BS*NA+255)/256, 256, 0, stream>>>(w_align, w_ovl, w_mask, gl, gtb,
                                               o_labels, o_bboxes, o_maskpos, o_gtidx, o_fg,
                                               w_pa, w_po);
  k_fuse<<<NB_FIX + (BS*NA+255)/256, 256, 0, stream>>>(gtb, mgt, w_mask,
                                                       o_gtdist, o_cent,
                                                       w_align, w_pa, w_po,
                                                       o_labels, o_fg, o_gtidx, o_scores);
}